// Round 7
// baseline (70.587 us; speedup 1.0000x reference)
//
#include <hip/hip_runtime.h>
#include <cmath>

#define SITE 8
#define DIM 16
#define BATCH 8192

// d_ws layout (floats), padded M: matrix r at r*272, row k at k*17 (16 used + 1 pad)
//   [0 .. 7616)      M table: 28 matrices, entry r*272 + k*17 + j ; r = s*4+bit*2+h
//   [7616 .. 7648)   head vectors hv[2][16]
#define WS_MPAD 272
#define WS_KPAD 17
#define WS_MEND 7616
#define WS_HV   7616

__device__ __forceinline__ float fast_tanh(float a) {
    // 1 - 2/(exp(2a)+1): exact limits at +-inf, ~1e-7 rel error, one v_exp_f32.
    float t = __expf(2.0f * a);
    return 1.0f - 2.0f / (t + 1.0f);
}

// Kernel A: build the 28 pattern-independent 16x16 matrices (float4 gathers)
// plus the 2 head vectors, into padded ws layout.
__global__ __launch_bounds__(256) void build_kernel(
    const float* __restrict__ embedding,  // (8,2,16)
    const float* __restrict__ head_w,     // (32,32)
    const float* __restrict__ body_w,     // (7,32,32,32)
    float* __restrict__ ws)
{
    const int tid = threadIdx.x;
    if (blockIdx.x < 7) {
        int t = blockIdx.x * 256 + tid;   // 0 .. 1791 ; one float4 of one matrix
        int r = t >> 6;                   // matrix 0..27: r = s*4 + bit*2 + h
        int rem = t & 63;
        int k  = rem >> 2;
        int j4 = rem & 3;
        int s   = r >> 2;
        int bit = (r >> 1) & 1;
        int h   = r & 1;
        int rowoff = (bit ^ h) << 4;      // +16 row block when bit^h
        int ioff   = bit << 4;            // +16 middle block when bit
        int coloff = (h << 4) + j4 * 4;   // +16 col block when h
        float sgn  = (bit && !h) ? -1.0f : 1.0f;
        const float* g3  = body_w + s * 32768 + (k + rowoff) * 1024 + ioff * 32 + coloff;
        const float* emb = embedding + (s + 1) * 32 + bit * 16;
        float4 acc = make_float4(0.f, 0.f, 0.f, 0.f);
        #pragma unroll
        for (int i = 0; i < 16; ++i) {
            float e = emb[i];
            float4 g = *(const float4*)(g3 + i * 32);
            acc.x += e * g.x; acc.y += e * g.y; acc.z += e * g.z; acc.w += e * g.w;
        }
        float* dst = ws + r * WS_MPAD + k * WS_KPAD + j4 * 4;  // stride-17 rows
        dst[0] = sgn * acc.x; dst[1] = sgn * acc.y;
        dst[2] = sgn * acc.z; dst[3] = sgn * acc.w;
    } else {
        if (tid < 32) {
            int h = tid >> 4;
            int j = tid & 15;
            const float* emb = embedding + h * 16;   // site 0, row h
            float a = 0.f;
            if (h == 0) {
                #pragma unroll
                for (int k = 0; k < 16; ++k) a += emb[k] * head_w[k * 32 + j];
            } else {
                #pragma unroll
                for (int k = 0; k < 16; ++k) a += emb[k] * head_w[(k + 16) * 32 + (j + 16)];
            }
            ws[WS_HV + h * 16 + j] = fast_tanh(a);
        }
    }
}

// Kernel B: fused recurrence + scatter, register-state + shuffle recurrence.
// 1024 blocks x 256 threads; 8 samples/block (32 lanes each, 2 per wave).
// NOTE: every __shfl is executed by ALL lanes (no divergent branches around
// cross-lane ops) — ds_bpermute returns garbage when the SOURCE lane is
// EXEC-masked off (R5's bug).
__global__ __launch_bounds__(256) void recur_scatter_kernel(
    const int* __restrict__ data,     // (8192,8)
    const float* __restrict__ ws,
    float2* __restrict__ out2)        // (8192,32) float2
{
    __shared__ __align__(16) float Ml[WS_MEND];

    const int tid = threadIdx.x;

    // stage padded M table: 1904 float4, coalesced
    #pragma unroll
    for (int it = 0; it < 8; ++it) {
        int i4 = tid + 256 * it;
        if (i4 < WS_MEND / 4)
            ((float4*)Ml)[i4] = ((const float4*)ws)[i4];
    }

    const int pl = tid >> 5;              // sample slot 0..7
    const int h  = (tid >> 4) & 1;
    const int j  = tid & 15;
    const int b  = blockIdx.x * 8 + pl;   // sample index

    // head value (L2-hot, overlaps LDS staging)
    float hvv = ws[WS_HV + h * 16 + j];

    // pattern id
    const int4* d4 = (const int4*)(data + b * 8);
    int4 w0 = d4[0];
    int4 w1 = d4[1];
    int id = (w0.x & 1) | ((w0.y & 1) << 1) | ((w0.z & 1) << 2) | ((w0.w & 1) << 3)
           | ((w1.x & 1) << 4) | ((w1.y & 1) << 5) | ((w1.z & 1) << 6) | ((w1.w & 1) << 7);

    __syncthreads();

    // state in a register; lane h*16+j of each 32-lane group holds v[h][j]
    float v = ((id & 1) == h) ? hvv : 0.f;   // predicated, not branched

    #pragma unroll
    for (int s = 1; s < SITE; ++s) {
        int bit = (id >> s) & 1;
        int srcbase = (h ^ bit) << 4;     // lane base of source half within group
        const float* m = Ml + ((s - 1) * 4 + bit * 2 + h) * WS_MPAD + j;
        float a0 = 0.f, a1 = 0.f, a2 = 0.f, a3 = 0.f;
        #pragma unroll
        for (int k = 0; k < 16; k += 4) {
            a0 += __shfl(v, srcbase + k,     32) * m[k * WS_KPAD];
            a1 += __shfl(v, srcbase + k + 1, 32) * m[(k + 1) * WS_KPAD];
            a2 += __shfl(v, srcbase + k + 2, 32) * m[(k + 2) * WS_KPAD];
            a3 += __shfl(v, srcbase + k + 3, 32) * m[(k + 3) * WS_KPAD];
        }
        v = fast_tanh((a0 + a1) + (a2 + a3));
    }

    // write row b as 32 float2: elements 0..15 = e (lanes 0..15),
    // 16..47 = zeros, 48..63 = o (lanes 16..31).
    // Shuffles run on ALL lanes; zeroing is predicated afterwards.
    {
        int l = tid & 31;                 // float2 index within the row
        int e0 = l * 2;                   // element pair (e0, e0+1)
        int src = (e0 < 16) ? e0 : ((e0 >= 48) ? (e0 - 32) : 0);
        float x0 = __shfl(v, src,     32);
        float x1 = __shfl(v, src + 1, 32);
        bool mid = (e0 >= 16) && (e0 < 48);
        if (mid) { x0 = 0.f; x1 = 0.f; }
        out2[b * 32 + l] = make_float2(x0, x1);
    }
}

extern "C" void kernel_launch(void* const* d_in, const int* in_sizes, int n_in,
                              void* d_out, int out_size, void* d_ws, size_t ws_size,
                              hipStream_t stream) {
    const int*   data      = (const int*)d_in[0];
    const float* embedding = (const float*)d_in[1];
    const float* head_w    = (const float*)d_in[2];
    const float* body_w    = (const float*)d_in[3];
    float* ws = (float*)d_ws;

    build_kernel<<<8, 256, 0, stream>>>(embedding, head_w, body_w, ws);
    recur_scatter_kernel<<<BATCH / 8, 256, 0, stream>>>(data, ws, (float2*)d_out);
}

// Round 8
// 66.660 us; speedup vs baseline: 1.0589x; 1.0589x over previous
//
#include <hip/hip_runtime.h>
#include <cmath>

#define SITE 8
#define DIM 16
#define BATCH 8192

// d_ws layout (floats), padded M: matrix r at r*272, row k at k*17 (16 used + 1 pad)
//   [0 .. 7616)      M table: 28 matrices, entry r*272 + k*17 + j ; r = s*4+bit*2+h
//   [7616 .. 7648)   head vectors hv[2][16]
#define WS_MPAD 272
#define WS_KPAD 17
#define WS_MEND 7616
#define WS_HV   7616

__device__ __forceinline__ float fast_tanh(float a) {
    // 1 - 2/(exp(2a)+1): exact limits at +-inf, ~1e-7 rel error, one v_exp_f32.
    float t = __expf(2.0f * a);
    return 1.0f - 2.0f / (t + 1.0f);
}

// Kernel A: build the 28 pattern-independent 16x16 matrices (float4 gathers)
// plus the 2 head vectors, into padded ws layout.
__global__ __launch_bounds__(256) void build_kernel(
    const float* __restrict__ embedding,  // (8,2,16)
    const float* __restrict__ head_w,     // (32,32)
    const float* __restrict__ body_w,     // (7,32,32,32)
    float* __restrict__ ws)
{
    const int tid = threadIdx.x;
    if (blockIdx.x < 7) {
        int t = blockIdx.x * 256 + tid;   // 0 .. 1791 ; one float4 of one matrix
        int r = t >> 6;                   // matrix 0..27: r = s*4 + bit*2 + h
        int rem = t & 63;
        int k  = rem >> 2;
        int j4 = rem & 3;
        int s   = r >> 2;
        int bit = (r >> 1) & 1;
        int h   = r & 1;
        int rowoff = (bit ^ h) << 4;      // +16 row block when bit^h
        int ioff   = bit << 4;            // +16 middle block when bit
        int coloff = (h << 4) + j4 * 4;   // +16 col block when h
        float sgn  = (bit && !h) ? -1.0f : 1.0f;
        const float* g3  = body_w + s * 32768 + (k + rowoff) * 1024 + ioff * 32 + coloff;
        const float* emb = embedding + (s + 1) * 32 + bit * 16;
        float4 acc = make_float4(0.f, 0.f, 0.f, 0.f);
        #pragma unroll
        for (int i = 0; i < 16; ++i) {
            float e = emb[i];
            float4 g = *(const float4*)(g3 + i * 32);
            acc.x += e * g.x; acc.y += e * g.y; acc.z += e * g.z; acc.w += e * g.w;
        }
        float* dst = ws + r * WS_MPAD + k * WS_KPAD + j4 * 4;  // stride-17 rows
        dst[0] = sgn * acc.x; dst[1] = sgn * acc.y;
        dst[2] = sgn * acc.z; dst[3] = sgn * acc.w;
    } else {
        if (tid < 32) {
            int h = tid >> 4;
            int j = tid & 15;
            const float* emb = embedding + h * 16;   // site 0, row h
            float a = 0.f;
            if (h == 0) {
                #pragma unroll
                for (int k = 0; k < 16; ++k) a += emb[k] * head_w[k * 32 + j];
            } else {
                #pragma unroll
                for (int k = 0; k < 16; ++k) a += emb[k] * head_w[(k + 16) * 32 + (j + 16)];
            }
            ws[WS_HV + h * 16 + j] = fast_tanh(a);
        }
    }
}

// Kernel B: fused recurrence + scatter (R4 structure — best measured).
// 1024 blocks x 256 threads; 8 samples/block, one 32-lane wave-local group
// per sample => barrier-free recurrence on LDS state (ds_read_b128-friendly).
__global__ __launch_bounds__(256) void recur_scatter_kernel(
    const int* __restrict__ data,     // (8192,8)
    const float* __restrict__ ws,
    float4* __restrict__ out4)        // (8192,16) float4
{
    __shared__ __align__(16) float Ml[WS_MEND];
    __shared__ __align__(16) float st[8][2][16];

    const int tid = threadIdx.x;

    // stage padded M table: 1904 float4, branch-free 7 iters + 112 tail
    #pragma unroll
    for (int it = 0; it < 7; ++it) {
        int i4 = tid + 256 * it;
        ((float4*)Ml)[i4] = ((const float4*)ws)[i4];
    }
    if (tid < 112) {
        int i4 = tid + 1792;
        ((float4*)Ml)[i4] = ((const float4*)ws)[i4];
    }

    const int pl = tid >> 5;              // group slot 0..7
    const int h  = (tid >> 4) & 1;
    const int j  = tid & 15;
    const int b  = blockIdx.x * 8 + pl;   // sample index

    // head value (L2-hot, overlaps LDS staging)
    float hvv = ws[WS_HV + h * 16 + j];

    // pattern id from the sample's 8 bits
    const int4* d4 = (const int4*)(data + b * 8);
    int4 w0 = d4[0];
    int4 w1 = d4[1];
    int id = (w0.x & 1) | ((w0.y & 1) << 1) | ((w0.z & 1) << 2) | ((w0.w & 1) << 3)
           | ((w1.x & 1) << 4) | ((w1.y & 1) << 5) | ((w1.z & 1) << 6) | ((w1.w & 1) << 7);

    __syncthreads();

    // init: bit0==h -> hv[h], else 0 (predicated)
    float v = ((id & 1) == h) ? hvv : 0.f;
    st[pl][h][j] = v;                     // wave-local LDS, no barrier needed

    #pragma unroll
    for (int s = 1; s < SITE; ++s) {
        int bit = (id >> s) & 1;
        const float* src = st[pl][h ^ bit];
        const float* m   = Ml + ((s - 1) * 4 + bit * 2 + h) * WS_MPAD;
        float a0 = 0.f, a1 = 0.f, a2 = 0.f, a3 = 0.f;
        #pragma unroll
        for (int k = 0; k < 16; k += 4) {
            a0 += src[k]     * m[k * WS_KPAD + j];
            a1 += src[k + 1] * m[(k + 1) * WS_KPAD + j];
            a2 += src[k + 2] * m[(k + 2) * WS_KPAD + j];
            a3 += src[k + 3] * m[(k + 3) * WS_KPAD + j];
        }
        v = fast_tanh((a0 + a1) + (a2 + a3));
        st[pl][h][j] = v;                 // lockstep within wave
    }

    // write row b: 16 float4 = [e(4), zeros(8), o(4)]; lanes 0..15 of group
    if ((tid & 31) < 16) {
        int q = j;                        // 0..15
        float4 v4 = make_float4(0.f, 0.f, 0.f, 0.f);
        if (q < 4)        v4 = *(const float4*)&st[pl][0][q * 4];
        else if (q >= 12) v4 = *(const float4*)&st[pl][1][(q - 12) * 4];
        out4[b * 16 + q] = v4;
    }
}

extern "C" void kernel_launch(void* const* d_in, const int* in_sizes, int n_in,
                              void* d_out, int out_size, void* d_ws, size_t ws_size,
                              hipStream_t stream) {
    const int*   data      = (const int*)d_in[0];
    const float* embedding = (const float*)d_in[1];
    const float* head_w    = (const float*)d_in[2];
    const float* body_w    = (const float*)d_in[3];
    float* ws = (float*)d_ws;

    build_kernel<<<8, 256, 0, stream>>>(embedding, head_w, body_w, ws);
    recur_scatter_kernel<<<BATCH / 8, 256, 0, stream>>>(data, ws, (float4*)d_out);
}